// Round 1
// baseline (1038.497 us; speedup 1.0000x reference)
//
#include <hip/hip_runtime.h>

// DiagonalSISOCell: out[v,d,q] = sum_n ns[v,d,n] * C[d,n,q]
//   ns = exp(-delta_v * exp(log_nA[d,n])) * state[v,d,n] + delta_v * x[v,d] * B[d,n]
//   delta_v = softplus(x[v,:] . w_delta + b_delta)
//
// Latency-bound before (VALU 10%, HBM 19%, occupancy 37%): block-wide
// __syncthreads convoyed waves although the ns tile is WAVE-PRIVATE, and
// 33.8KB LDS capped 4 blocks/CU. Now: wave-level ordering only (no s_barrier),
// CD=4 chunks -> 4.3KB LDS/wave, 128-thread blocks, launch_bounds(128,8)
// -> up to 8 waves/SIMD of TLP to hide the per-chunk HBM state-load latency.

constexpr int D = 64;
constexpr int N = 16;
constexpr int VPW = 16;                 // v per wave
constexpr int WPB = 2;                  // waves per block (32 v/block -> 3125 blocks)
constexpr int CD  = 4;                  // d-chunk size
constexpr int NCHUNK = D / CD;          // 16
constexpr int NS_STRIDE = CD * N + 4;   // 68 floats (stride%32==4 -> 2-way banks, free)

__global__ __launch_bounds__(WPB * 64, 8)
void siso_kernel(const float* __restrict__ x,
                 const float* __restrict__ state,
                 const float* __restrict__ log_nA,
                 const float* __restrict__ Bm,
                 const float* __restrict__ Cm,
                 const float* __restrict__ w_delta,
                 const float* __restrict__ b_delta,
                 float* __restrict__ out,
                 int V)
{
    __shared__ __align__(16) float ns_lds[WPB][VPW * NS_STRIDE];  // 2*4352B = 8704B

    const int tid  = threadIdx.x;
    const int wave = tid >> 6;
    const int lane = tid & 63;
    float* nsw = ns_lds[wave];

    const int vbase = blockIdx.x * (WPB * VPW) + wave * VPW;

    // ---------- phase 0: delta for this wave's 16 v's ----------
    // lane = vv0*4 + kk ; each lane dots 16 elements of x[v0,:] with w_delta
    const int vv0 = lane >> 2;   // 0..15
    const int kk  = lane & 3;    // 0..3
    const int v0  = vbase + vv0;
    float z = 0.f;
    if (v0 < V) {
        const float4* xr = (const float4*)(x + (size_t)v0 * D) + kk * 4;
        const float4* wr = (const float4*)(w_delta) + kk * 4;
#pragma unroll
        for (int c = 0; c < 4; ++c) {
            float4 xv = xr[c];
            float4 wv = wr[c];
            z += xv.x * wv.x + xv.y * wv.y + xv.z * wv.z + xv.w * wv.w;
        }
    }
    z += __shfl_xor(z, 1, 64);
    z += __shfl_xor(z, 2, 64);
    z += b_delta[0];
    const float delta0 = (z > 20.f) ? z : __logf(1.f + __expf(z));
    // lane holds delta for v = vbase + (lane>>2)

    // ---------- loop-invariant lane roles ----------
    const int within = lane & 15;        // float4 slot inside a v's (CD x N) row-chunk
    const int vsub   = lane >> 4;        // 0..3 (phase-1 v sub-index)
    const int doffl  = within >> 2;      // 0..3 (phase-1 d offset)
    const int qg     = lane & 3;         // phase-2 q-group
    const int vv     = lane >> 2;        // phase-2 v index within wave
    const int v2     = vbase + vv;

    // delta values this lane needs in phase 1 are fixed across chunks: hoist shuffles
    float dl[4];
#pragma unroll
    for (int j = 0; j < 4; ++j)
        dl[j] = __shfl(delta0, (j * 4 + vsub) * 4, 64);

    for (int dc = 0; dc < NCHUNK; ++dc) {
        const int dbase = dc * CD;

        // ---------- phase 1: ns for d in [dbase, dbase+CD), 16 v's ----------
        // per-chunk invariants (were reloaded/recomputed 8x per chunk before):
        const float4 ga = ((const float4*)log_nA)[dbase * 4 + within];
        const float4 gb = ((const float4*)Bm)[dbase * 4 + within];
        float4 na;                        // exp(log_nA) hoisted out of the v loop
        na.x = __expf(ga.x); na.y = __expf(ga.y);
        na.z = __expf(ga.z); na.w = __expf(ga.w);

#pragma unroll
        for (int j = 0; j < 4; ++j) {
            const int voff = j * 4 + vsub;               // 0..15
            const int v    = vbase + voff;
            float4 s = make_float4(0.f, 0.f, 0.f, 0.f);
            float  xv = 0.f;
            if (v < V) {
                // lanes 0..15 cover one v's 256B chunk contiguously
                s  = ((const float4*)(state + (size_t)v * (D * N)))[dbase * 4 + within];
                xv = x[(size_t)v * D + dbase + doffl];
            }
            const float dj = dl[j];
            const float dx = dj * xv;
            float4 ns;
            ns.x = __expf(-dj * na.x) * s.x + dx * gb.x;
            ns.y = __expf(-dj * na.y) * s.y + dx * gb.y;
            ns.z = __expf(-dj * na.z) * s.z + dx * gb.z;
            ns.w = __expf(-dj * na.w) * s.w + dx * gb.w;
            *(float4*)(nsw + voff * NS_STRIDE + within * 4) = ns;
        }
        // tile is WAVE-private: draining this wave's ds_writes is all the sync needed
        asm volatile("s_waitcnt lgkmcnt(0)" ::: "memory");

        // ---------- phase 2: contraction over n, write out ----------
        if (v2 < V) {
            const float4* nsq = (const float4*)(nsw + vv * NS_STRIDE);  // 68%4==0: aligned
#pragma unroll
            for (int doff = 0; doff < CD; ++doff) {
                const int d = dbase + doff;
                const float* Crow = Cm + (size_t)d * (N * N) + qg * 4;  // C[d][n][4qg..]
                float4 acc = make_float4(0.f, 0.f, 0.f, 0.f);
#pragma unroll
                for (int n4 = 0; n4 < 4; ++n4) {
                    const float4 a  = nsq[doff * 4 + n4];               // ds_read_b128
                    const float4 c0 = *(const float4*)(Crow + (n4 * 4 + 0) * N);
                    const float4 c1 = *(const float4*)(Crow + (n4 * 4 + 1) * N);
                    const float4 c2 = *(const float4*)(Crow + (n4 * 4 + 2) * N);
                    const float4 c3 = *(const float4*)(Crow + (n4 * 4 + 3) * N);
                    acc.x += a.x * c0.x + a.y * c1.x + a.z * c2.x + a.w * c3.x;
                    acc.y += a.x * c0.y + a.y * c1.y + a.z * c2.y + a.w * c3.y;
                    acc.z += a.x * c0.z + a.y * c1.z + a.z * c2.z + a.w * c3.z;
                    acc.w += a.x * c0.w + a.y * c1.w + a.z * c2.w + a.w * c3.w;
                }
                *(float4*)(out + (size_t)v2 * (D * N) + d * N + qg * 4) = acc;
            }
        }
        // WAR vs next chunk's ds_writes: DS pipe is in-order per wave, so only a
        // compiler fence is needed (also keeps next state loads from hoisting above
        // this phase's C loads, which would entangle them in the vmcnt FIFO).
        asm volatile("" ::: "memory");
    }
}

extern "C" void kernel_launch(void* const* d_in, const int* in_sizes, int n_in,
                              void* d_out, int out_size, void* d_ws, size_t ws_size,
                              hipStream_t stream) {
    const float* x       = (const float*)d_in[0];
    const float* state   = (const float*)d_in[1];
    const float* log_nA  = (const float*)d_in[2];
    const float* Bm      = (const float*)d_in[3];
    const float* Cm      = (const float*)d_in[4];
    const float* w_delta = (const float*)d_in[5];
    const float* b_delta = (const float*)d_in[6];
    float* out = (float*)d_out;

    const int V = in_sizes[0] / D;                         // 100000
    const int blocks = (V + WPB * VPW - 1) / (WPB * VPW);  // 32 v per block -> 3125

    siso_kernel<<<blocks, WPB * 64, 0, stream>>>(x, state, log_nA, Bm, Cm,
                                                 w_delta, b_delta, out, V);
}